// Round 8
// baseline (120.557 us; speedup 1.0000x reference)
//
#include <hip/hip_runtime.h>
#include <cstdint>
#include <cmath>

typedef unsigned short u16;
typedef short bf16x8 __attribute__((ext_vector_type(8)));
typedef float f32x4 __attribute__((ext_vector_type(4)));

#define T_DIM 2048
#define B_DIM 16
#define CIN 512
#define COUT 512
#define KIN 1536
#define NROWS (T_DIM * B_DIM)        /* 32768 */
#define UROWS ((T_DIM + 2) * B_DIM)  /* 32800 */

#define NS 48                        /* K half-steps of 32 */

#define LOG2E 1.44269504088896f
#define LN2   0.69314718055995f

__device__ __forceinline__ float fast_exp2(float x) {
#if __has_builtin(__builtin_amdgcn_exp2f)
  return __builtin_amdgcn_exp2f(x);
#else
  return __builtin_exp2f(x);
#endif
}
__device__ __forceinline__ float fast_log2(float x) {
#if __has_builtin(__builtin_amdgcn_logf)
  return __builtin_amdgcn_logf(x);   // v_log_f32 = log2(x)
#else
  return __builtin_log2f(x);
#endif
}
__device__ __forceinline__ float fast_rcp(float x) {
  return __builtin_amdgcn_rcpf(x);
}

__device__ __forceinline__ u16 f2bf(float f) {
  unsigned u = __builtin_bit_cast(unsigned, f);
  u = (u + 0x7FFFu + ((u >> 16) & 1u)) >> 16;   // RNE
  return (u16)u;
}

typedef __attribute__((address_space(3))) unsigned int as3u32;
typedef __attribute__((address_space(1))) unsigned int as1u32;

// async global->LDS, 16B per lane; lds must be the wave-uniform base.
__device__ __forceinline__ void gload16(const u16* g, const u16* lds) {
#if __has_builtin(__builtin_amdgcn_global_load_lds)
  __builtin_amdgcn_global_load_lds((as1u32*)(uintptr_t)g,
                                   (as3u32*)(unsigned)(uintptr_t)lds, 16, 0, 0);
#else
  unsigned lane = __lane_id();
  ((uint4*)lds)[lane] = *(const uint4*)g;
#endif
}

// ---- K0a: partial column sumsq of weight_v [KIN, COUT], coalesced ----
__global__ __launch_bounds__(256) void k_colnorm(const float* __restrict__ wv,
                                                 float* __restrict__ partial) {
  int o = blockIdx.x * 256 + threadIdx.x;
  int r0 = blockIdx.y * 64;
  float s = 0.f;
#pragma unroll 8
  for (int r = 0; r < 64; ++r) {
    float v = wv[(size_t)(r0 + r) * COUT + o];
    s += v * v;
  }
  partial[(size_t)blockIdx.y * COUT + o] = s;
}

// ---- K0c: finalize invn ----
__global__ __launch_bounds__(256) void k_fin(const float* __restrict__ partial,
                                             float* __restrict__ invn) {
  int o = blockIdx.x * 256 + threadIdx.x;
  float s = 0.f;
#pragma unroll
  for (int j = 0; j < KIN / 64; ++j) s += partial[(size_t)j * COUT + o];
  invn[o] = 1.f / fmaxf(sqrtf(s), 1e-15f);
}

// ---- K0b: per-channel cosh/sinh of 2*bias ----
__global__ void k_chsh(const float* __restrict__ bias, float* __restrict__ ch,
                       float* __restrict__ sh) {
  int o = blockIdx.x * blockDim.x + threadIdx.x;
  if (o < COUT) {
    float d = 2.f * bias[o];
    float e = fast_exp2(d * LOG2E);
    float ie = fast_rcp(e);
    ch[o] = 0.5f * (e + ie);
    sh[o] = 0.5f * (e - ie);
  }
}

// ---- K1: W^T bf16: wt[o][i] = wv[i][o] * invn[o] ----
__global__ void k_wt(const float* __restrict__ wv, const float* __restrict__ invn,
                     u16* __restrict__ wt) {
  __shared__ float tile[64][65];
  int i0 = blockIdx.x * 64;
  int o0 = blockIdx.y * 64;
  int tx = threadIdx.x & 63, ty = threadIdx.x >> 6;  // 256 thr
  for (int r = ty; r < 64; r += 4)
    tile[r][tx] = wv[(size_t)(i0 + r) * COUT + o0 + tx];
  __syncthreads();
  for (int r = ty; r < 64; r += 4) {
    float inv = invn[o0 + r];
    wt[(size_t)(o0 + r) * KIN + i0 + tx] = f2bf(tile[tx][r] * inv);
  }
}

// ---- K2: u = logmap0(x)*BETA_RATIO -> bf16 [UROWS,512]; nsq fp32 per row ----
__global__ void k_logmap(const float* __restrict__ x, u16* __restrict__ U,
                         float* __restrict__ nsq, float beta_ratio) {
  int row = blockIdx.x;        // 0..32799 = t_pad*16 + b
  int t = row >> 4;
  int lane = threadIdx.x;      // 64
  uint4* urow = (uint4*)(U + (size_t)row * CIN);
  if (t == 0 || t == T_DIM + 1) {
    uint4 z; z.x = z.y = z.z = z.w = 0u;
    urow[lane] = z;
    if (lane == 0) nsq[row] = 0.f;
    return;
  }
  const float4* xr = (const float4*)(x + (size_t)(row - 16) * CIN);
  float4 a = xr[lane * 2];
  float4 b = xr[lane * 2 + 1];
  float s = a.x*a.x + a.y*a.y + a.z*a.z + a.w*a.w
          + b.x*b.x + b.y*b.y + b.z*b.z + b.w*b.w;
#pragma unroll
  for (int d = 1; d < 64; d <<= 1) s += __shfl_xor(s, d);
  float r = sqrtf(s);
  float yn = fmaxf(r, 1e-15f);
  float arg = fminf(yn, 1.0f - 1e-7f);
  float at = 0.5f * LN2 * fast_log2((1.f + arg) * fast_rcp(1.f - arg));
  float f = at / yn * beta_ratio;
  union { u16 h[8]; uint4 v; } pk;
  pk.h[0] = f2bf(a.x * f); pk.h[1] = f2bf(a.y * f);
  pk.h[2] = f2bf(a.z * f); pk.h[3] = f2bf(a.w * f);
  pk.h[4] = f2bf(b.x * f); pk.h[5] = f2bf(b.y * f);
  pk.h[6] = f2bf(b.z * f); pk.h[7] = f2bf(b.w * f);
  urow[lane] = pk.v;
  if (lane == 0) nsq[row] = s * f * f;
}

// ---- K3: GEMM dot[m][o] = sum_k u_im2col[m][k] * wt[o][k] ----
// 256x256 tile, half-K steps of 32, 4-deep LDS ring (128 KiB), 8 waves
// (2M x 4N, wave 128x64, acc[8][4]). Two phases per step with counted vmcnt
// (never 0 mid-loop): loads for step s+3 issue while computing s; buffer b
// is overwritten only 3 steps later, after its readers' lgkm+barrier fence.
// Swizzle: phys k-chunk = c ^ ((row>>1)&3) within [row][32]u16 (64B rows);
// staging pre-swizzles the GLOBAL source chunk, gload dests stay linear.
__global__ __launch_bounds__(512, 2) void k_gemm(const u16* __restrict__ U,
                                                 const u16* __restrict__ WT,
                                                 float* __restrict__ out) {
  __shared__ u16 lA[4][256 * 32];   // 4 x 16 KiB
  __shared__ u16 lB[4][256 * 32];   // 4 x 16 KiB
  int bid = blockIdx.x;
  // XCD-contiguous: 32 consecutive wgids per XCD; bn-pairs adjacent.
  int wgid = (bid & 7) * 32 + (bid >> 3);
  int bm = wgid >> 1, bn = wgid & 1;
  int tid = threadIdx.x;
  int lane = tid & 63;
  int wid = tid >> 6;
  int wr = wid >> 2, wc = wid & 3;      // wave tile: 128 rows x 64 cols
  int lr = lane & 15;
  // frag read: phys chunk = (lane>>4) ^ ((lr>>1)&3)  (row base mult of 16)
  int pcA = (((lane >> 4) ^ ((lr >> 1) & 3)) << 3);
  // staging: thread covers row r*128 + (tid>>2), chunk-in-row tid&3
  int srow0 = tid >> 2;
  int cir = tid & 3;

  f32x4 acc[8][4] = {};

  auto STG_A = [&](int s, int p) {
    int seg = s >> 4;                    // conv tap 0..2
    int c0 = (s & 15) << 5;              // col offset within tap
#pragma unroll
    for (int r = 0; r < 2; ++r) {
      int row = r * 128 + srow0;
      int sc = cir ^ ((row >> 1) & 3);
      gload16(U + (size_t)(bm * 256 + seg * 16 + row) * 512 + c0 + sc * 8,
              &lA[p][(r * 128 + wid * 16) * 32]);
    }
  };
  auto STG_B = [&](int s, int p) {
#pragma unroll
    for (int r = 0; r < 2; ++r) {
      int row = r * 128 + srow0;
      int sc = cir ^ ((row >> 1) & 3);
      gload16(WT + (size_t)(bn * 256 + row) * KIN + s * 32 + sc * 8,
              &lB[p][(r * 128 + wid * 16) * 32]);
    }
  };

  STG_A(0, 0); STG_B(0, 0);
  STG_A(1, 1); STG_B(1, 1);
  STG_A(2, 2); STG_B(2, 2);

  for (int s = 0; s < NS; ++s) {
    int b = s & 3, pb = (s + 3) & 3;
    // ---------- Phase A ----------
    if (s < NS - 3) STG_A(s + 3, pb);
    if (s < NS - 3)      asm volatile("s_waitcnt vmcnt(10)" ::: "memory");
    else if (s == NS - 3) asm volatile("s_waitcnt vmcnt(8)" ::: "memory");
    else if (s == NS - 2) asm volatile("s_waitcnt vmcnt(4)" ::: "memory");
    else                  asm volatile("s_waitcnt vmcnt(0)" ::: "memory");
    asm volatile("s_barrier" ::: "memory");
    const u16* pA = &lA[b][(wr * 128 + lr) * 32 + pcA];
    const u16* pB = &lB[b][(wc * 64 + lr) * 32 + pcA];
    bf16x8 af0[4], af1[4], bfr[4];
#pragma unroll
    for (int i = 0; i < 4; ++i) af0[i] = *(const bf16x8*)(pA + i * 512);
#pragma unroll
    for (int i = 0; i < 4; ++i) bfr[i] = *(const bf16x8*)(pB + i * 512);
    __builtin_amdgcn_s_setprio(1);
#pragma unroll
    for (int mi = 0; mi < 4; ++mi)
#pragma unroll
      for (int ni = 0; ni < 4; ++ni)
        acc[mi][ni] = __builtin_amdgcn_mfma_f32_16x16x32_bf16(
            af0[mi], bfr[ni], acc[mi][ni], 0, 0, 0);
    __builtin_amdgcn_s_setprio(0);
    asm volatile("s_barrier" ::: "memory");
    // ---------- Phase B ----------
    if (s < NS - 3) STG_B(s + 3, pb);
#pragma unroll
    for (int i = 0; i < 4; ++i) af1[i] = *(const bf16x8*)(pA + (64 + i * 16) * 32);
    __builtin_amdgcn_s_setprio(1);
#pragma unroll
    for (int mi = 0; mi < 4; ++mi)
#pragma unroll
      for (int ni = 0; ni < 4; ++ni)
        acc[4 + mi][ni] = __builtin_amdgcn_mfma_f32_16x16x32_bf16(
            af1[mi], bfr[ni], acc[4 + mi][ni], 0, 0, 0);
    __builtin_amdgcn_s_setprio(0);
    asm volatile("s_waitcnt lgkmcnt(0)" ::: "memory");  // buf b reads fenced
    asm volatile("s_barrier" ::: "memory");
  }

  int orow = bm * 256 + wr * 128 + ((lane >> 4) << 2);
  int ocol = bn * 256 + wc * 64 + lr;
#pragma unroll
  for (int mi = 0; mi < 8; ++mi)
#pragma unroll
    for (int ni = 0; ni < 4; ++ni)
#pragma unroll
      for (int j = 0; j < 4; ++j)
        out[(size_t)(orow + mi * 16 + j) * COUT + (ocol + ni * 16)] = acc[mi][ni][j];
}

// ---- K4: in-place epilogue on dot rows: poincare_linear tail + project ----
__global__ __launch_bounds__(128) void k_epi(float* __restrict__ out,
                                             const float* __restrict__ nsq,
                                             const float* __restrict__ wg,
                                             const float* __restrict__ chv,
                                             const float* __restrict__ shv) {
  int m = blockIdx.x;
  int tid = threadIdx.x;                 // 128
  int lane = tid & 63, wv_ = tid >> 6;
  float un2 = nsq[m] + nsq[m + 16] + nsq[m + 32];
  float un = sqrtf(un2);
  float unc = fmaxf(un, 1e-15f);
  float e2 = fast_exp2(unc * (2.f * LOG2E));
  float th = (e2 - 1.f) * fast_rcp(e2 + 1.f);
  float sxp = th * fast_rcp(unc);        // expmap0 scale (RC=1)
  float cx2 = sxp * sxp * un2;           // ||rcx||^2
  float iden = fast_rcp(fmaxf(1.f - cx2, 1e-15f));

  float4 dv = ((const float4*)(out + (size_t)m * COUT))[tid];
  float4 gv = ((const float4*)wg)[tid];
  float4 cv = ((const float4*)chv)[tid];
  float4 sv = ((const float4*)shv)[tid];
  float dot[4] = {dv.x, dv.y, dv.z, dv.w};
  float gvr[4] = {gv.x, gv.y, gv.z, gv.w};
  float chr[4] = {cv.x, cv.y, cv.z, cv.w};
  float shr[4] = {sv.x, sv.y, sv.z, sv.w};
  float y[4];
  float opc = 1.f + cx2;
#pragma unroll
  for (int e = 0; e < 4; ++e) {
    float num = 2.f * (sxp * dot[e]) * chr[e] - opc * shr[e];
    float z = num * iden;
    float w = z + sqrtf(fmaf(z, z, 1.f));
    float l = fast_log2(w);
    float E = fast_exp2((2.f * gvr[e]) * l);
    y[e] = 0.5f * (E - fast_rcp(E));
  }
  float ssl = y[0]*y[0] + y[1]*y[1] + y[2]*y[2] + y[3]*y[3];
#pragma unroll
  for (int d = 1; d < 64; d <<= 1) ssl += __shfl_xor(ssl, d);
  __shared__ float red[2];
  if (lane == 0) red[wv_] = ssl;
  __syncthreads();
  float ss = red[0] + red[1];
  float denom = 1.f + sqrtf(1.f + ss);
  float idn = 1.f / denom;
  float nrm = fmaxf(sqrtf(ss) * idn, 1e-15f);
  float maxn = 1.0f - 4e-3f;
  float scale = (nrm > maxn) ? (maxn / nrm) : 1.f;
  scale *= idn;
  float4 ov;
  ov.x = y[0] * scale;
  ov.y = y[1] * scale;
  ov.z = y[2] * scale;
  ov.w = y[3] * scale;
  ((float4*)(out + (size_t)m * COUT))[tid] = ov;
}

extern "C" void kernel_launch(void* const* d_in, const int* in_sizes, int n_in,
                              void* d_out, int out_size, void* d_ws, size_t ws_size,
                              hipStream_t stream) {
  const float* x    = (const float*)d_in[0];
  const float* wg   = (const float*)d_in[1];
  const float* wv   = (const float*)d_in[2];
  const float* bias = (const float*)d_in[3];
  float* out = (float*)d_out;

  char* ws = (char*)d_ws;
  u16*   U    = (u16*)(ws);                    // 2050*16*512 bf16 = 33,587,200 B
  float* NSQ  = (float*)(ws + 33587200);       // 32800 f32      =    131,200 B
  u16*   WT   = (u16*)(ws + 33718400);         // 512*1536 bf16  =  1,572,864 B
  float* INVN = (float*)(ws + 35291264);       // 512 f32
  float* CH   = (float*)(ws + 35293312);       // 512 f32
  float* SH   = (float*)(ws + 35295360);       // 512 f32
  float* PART = (float*)(ws + 35297408);       // 24*512 f32 = 49,152 B

  double lb = (lgamma(768.0) + lgamma(0.5) - lgamma(768.5))
            - (lgamma(256.0) + lgamma(0.5) - lgamma(256.5));
  float beta_ratio = (float)exp(lb);           // beta(768,.5)/beta(256,.5)

  k_colnorm<<<dim3(COUT / 256, KIN / 64), 256, 0, stream>>>(wv, PART);
  k_fin<<<COUT / 256, 256, 0, stream>>>(PART, INVN);
  k_chsh<<<COUT / 128, 128, 0, stream>>>(bias, CH, SH);
  k_wt<<<dim3(KIN / 64, COUT / 64), 256, 0, stream>>>(wv, INVN, WT);
  k_logmap<<<UROWS, 64, 0, stream>>>(x, U, NSQ, beta_ratio);
  k_gemm<<<(NROWS / 256) * (COUT / 256), 512, 0, stream>>>(U, WT, out);
  k_epi<<<NROWS, 128, 0, stream>>>(out, NSQ, wg, CH, SH);
}

// Round 9
// 118.055 us; speedup vs baseline: 1.0212x; 1.0212x over previous
//
#include <hip/hip_runtime.h>
#include <cstdint>
#include <cmath>

typedef unsigned short u16;
typedef short bf16x8 __attribute__((ext_vector_type(8)));
typedef float f32x4 __attribute__((ext_vector_type(4)));

#define T_DIM 2048
#define B_DIM 16
#define CIN 512
#define COUT 512
#define KIN 1536
#define NROWS (T_DIM * B_DIM)        /* 32768 */
#define UROWS ((T_DIM + 2) * B_DIM)  /* 32800 */

#define NTILES 24                    /* K-tiles of 64 */

#define LOG2E 1.44269504088896f
#define LN2   0.69314718055995f

__device__ __forceinline__ float fast_exp2(float x) {
#if __has_builtin(__builtin_amdgcn_exp2f)
  return __builtin_amdgcn_exp2f(x);
#else
  return __builtin_exp2f(x);
#endif
}
__device__ __forceinline__ float fast_log2(float x) {
#if __has_builtin(__builtin_amdgcn_logf)
  return __builtin_amdgcn_logf(x);   // v_log_f32 = log2(x)
#else
  return __builtin_log2f(x);
#endif
}
__device__ __forceinline__ float fast_rcp(float x) {
  return __builtin_amdgcn_rcpf(x);
}

__device__ __forceinline__ u16 f2bf(float f) {
  unsigned u = __builtin_bit_cast(unsigned, f);
  u = (u + 0x7FFFu + ((u >> 16) & 1u)) >> 16;   // RNE
  return (u16)u;
}

typedef __attribute__((address_space(3))) unsigned int as3u32;
typedef __attribute__((address_space(1))) unsigned int as1u32;

// async global->LDS, 16B per lane; lds must be the wave-uniform base.
__device__ __forceinline__ void gload16(const u16* g, const u16* lds) {
#if __has_builtin(__builtin_amdgcn_global_load_lds)
  __builtin_amdgcn_global_load_lds((as1u32*)(uintptr_t)g,
                                   (as3u32*)(unsigned)(uintptr_t)lds, 16, 0, 0);
#else
  unsigned lane = __lane_id();
  ((uint4*)lds)[lane] = *(const uint4*)g;
#endif
}

// ---- K0a: partial column sumsq of weight_v [KIN, COUT], coalesced ----
__global__ __launch_bounds__(256) void k_colnorm(const float* __restrict__ wv,
                                                 float* __restrict__ partial) {
  int o = blockIdx.x * 256 + threadIdx.x;
  int r0 = blockIdx.y * 64;
  float s = 0.f;
#pragma unroll 8
  for (int r = 0; r < 64; ++r) {
    float v = wv[(size_t)(r0 + r) * COUT + o];
    s += v * v;
  }
  partial[(size_t)blockIdx.y * COUT + o] = s;
}

// ---- K0c: finalize invn ----
__global__ __launch_bounds__(256) void k_fin(const float* __restrict__ partial,
                                             float* __restrict__ invn) {
  int o = blockIdx.x * 256 + threadIdx.x;
  float s = 0.f;
#pragma unroll
  for (int j = 0; j < KIN / 64; ++j) s += partial[(size_t)j * COUT + o];
  invn[o] = 1.f / fmaxf(sqrtf(s), 1e-15f);
}

// ---- K0b: per-channel cosh/sinh of 2*bias ----
__global__ void k_chsh(const float* __restrict__ bias, float* __restrict__ ch,
                       float* __restrict__ sh) {
  int o = blockIdx.x * blockDim.x + threadIdx.x;
  if (o < COUT) {
    float d = 2.f * bias[o];
    float e = fast_exp2(d * LOG2E);
    float ie = fast_rcp(e);
    ch[o] = 0.5f * (e + ie);
    sh[o] = 0.5f * (e - ie);
  }
}

// ---- K1: W^T bf16: wt[o][i] = wv[i][o] * invn[o] ----
__global__ void k_wt(const float* __restrict__ wv, const float* __restrict__ invn,
                     u16* __restrict__ wt) {
  __shared__ float tile[64][65];
  int i0 = blockIdx.x * 64;
  int o0 = blockIdx.y * 64;
  int tx = threadIdx.x & 63, ty = threadIdx.x >> 6;  // 256 thr
  for (int r = ty; r < 64; r += 4)
    tile[r][tx] = wv[(size_t)(i0 + r) * COUT + o0 + tx];
  __syncthreads();
  for (int r = ty; r < 64; r += 4) {
    float inv = invn[o0 + r];
    wt[(size_t)(o0 + r) * KIN + i0 + tx] = f2bf(tile[tx][r] * inv);
  }
}

// ---- K2: u = logmap0(x)*BETA_RATIO -> bf16 [UROWS,512]; nsq fp32 per row ----
__global__ void k_logmap(const float* __restrict__ x, u16* __restrict__ U,
                         float* __restrict__ nsq, float beta_ratio) {
  int row = blockIdx.x;        // 0..32799 = t_pad*16 + b
  int t = row >> 4;
  int lane = threadIdx.x;      // 64
  uint4* urow = (uint4*)(U + (size_t)row * CIN);
  if (t == 0 || t == T_DIM + 1) {
    uint4 z; z.x = z.y = z.z = z.w = 0u;
    urow[lane] = z;
    if (lane == 0) nsq[row] = 0.f;
    return;
  }
  const float4* xr = (const float4*)(x + (size_t)(row - 16) * CIN);
  float4 a = xr[lane * 2];
  float4 b = xr[lane * 2 + 1];
  float s = a.x*a.x + a.y*a.y + a.z*a.z + a.w*a.w
          + b.x*b.x + b.y*b.y + b.z*b.z + b.w*b.w;
#pragma unroll
  for (int d = 1; d < 64; d <<= 1) s += __shfl_xor(s, d);
  float r = sqrtf(s);
  float yn = fmaxf(r, 1e-15f);
  float arg = fminf(yn, 1.0f - 1e-7f);
  float at = 0.5f * LN2 * fast_log2((1.f + arg) * fast_rcp(1.f - arg));
  float f = at / yn * beta_ratio;
  union { u16 h[8]; uint4 v; } pk;
  pk.h[0] = f2bf(a.x * f); pk.h[1] = f2bf(a.y * f);
  pk.h[2] = f2bf(a.z * f); pk.h[3] = f2bf(a.w * f);
  pk.h[4] = f2bf(b.x * f); pk.h[5] = f2bf(b.y * f);
  pk.h[6] = f2bf(b.z * f); pk.h[7] = f2bf(b.w * f);
  urow[lane] = pk.v;
  if (lane == 0) nsq[row] = s * f * f;
}

// ---- K3: GEMM, m201-style 8-phase schedule ----
// 256x256 tile, BK=64 in 2 K-halves of 32, LDS [buf][khalf][256][32]u16
// (128 KiB). 8 waves (2M x 4N), wave 128x64, acc[8][4]. Per K-tile: 4
// quadrant-phases (q = kkhalf*2 + mihalf), each: {4-8 ds_read_b128 ->
// stage 1 half-tile (2 gloads) -> s_barrier -> lgkmcnt(0) -> setprio(1)
// -> 16 MFMA -> setprio(0) -> s_barrier}. Stage map per tile t: q0->
// A1(t+1), q1->B0(t+2), q2->A0(t+2), q3->B1(t+2); every region's last
// read is lgkm-fenced one barrier before its overwrite. vmcnt(6) once
// per tile (3 half-tiles in flight). Swizzle: chunk ^= (row>>1)&3 within
// 64B rows (exact 2-way aliasing = free); pre-swizzled global source.
__global__ __launch_bounds__(512, 2) void k_gemm(const u16* __restrict__ U,
                                                 const u16* __restrict__ WT,
                                                 float* __restrict__ out) {
  __shared__ u16 lA[2][2][8192];   // [buf][khalf][256*32]
  __shared__ u16 lB[2][2][8192];
  int bid = blockIdx.x;
  // XCD-contiguous: 32 consecutive wgids per XCD; bn-pairs adjacent.
  int wgid = (bid & 7) * 32 + (bid >> 3);
  int bm = wgid >> 1, bn = wgid & 1;
  int tid = threadIdx.x;
  int lane = tid & 63;
  int wid = tid >> 6;
  int wr = wid >> 2, wc = wid & 3;      // wave tile: 128 rows x 64 cols
  int lr = lane & 15;
  int srow = tid >> 2;                  // staging row (0..127), +128 for 2nd
  int sc = (tid & 3) ^ ((tid >> 3) & 3);        // pre-swizzled src chunk
  int cSwz = ((lane >> 4) ^ ((lr >> 1) & 3)) << 3;  // frag read chunk (u16)

  f32x4 acc[8][4] = {};

  auto stgA = [&](int tt, int h) {
    int ks32 = tt * 2 + h;
    int seg = ks32 >> 4;                 // conv tap 0..2
    int c0 = (ks32 & 15) << 5;           // col offset within tap
    const u16* g = U + (size_t)(bm * 256 + seg * 16 + srow) * 512 + c0 + sc * 8;
    const u16* d = &lA[tt & 1][h][wid * 512];
    gload16(g, d);
    gload16(g + (size_t)128 * 512, d + 4096);
  };
  auto stgB = [&](int tt, int h) {
    int ks32 = tt * 2 + h;
    const u16* g = WT + (size_t)(bn * 256 + srow) * KIN + ks32 * 32 + sc * 8;
    const u16* d = &lB[tt & 1][h][wid * 512];
    gload16(g, d);
    gload16(g + (size_t)128 * KIN, d + 4096);
  };

  // prologue: tile0 complete + tile1 {B0,A0,B1} = 7 half-tiles, 14 loads
  stgA(0, 0); stgB(0, 0); stgA(0, 1); stgB(0, 1);
  stgB(1, 0); stgA(1, 0); stgB(1, 1);
  asm volatile("s_waitcnt vmcnt(6)" ::: "memory");   // tile0 landed
  asm volatile("s_barrier" ::: "memory");

  for (int t = 0; t < NTILES; ++t) {
    int b = t & 1;
    const u16* pA = &lA[b][0][(wr * 128 + lr) * 32 + cSwz];
    const u16* pB = &lB[b][0][(wc * 64 + lr) * 32 + cSwz];
    bf16x8 af[4], bf[4];

    // ---- q0: kk=0, mi 0-3 ----
#pragma unroll
    for (int i = 0; i < 4; ++i) bf[i] = *(const bf16x8*)(pB + i * 512);
#pragma unroll
    for (int i = 0; i < 4; ++i) af[i] = *(const bf16x8*)(pA + i * 512);
    if (t + 1 < NTILES) stgA(t + 1, 1);
    asm volatile("s_barrier" ::: "memory");
    asm volatile("s_waitcnt lgkmcnt(0)" ::: "memory");
    __builtin_amdgcn_s_setprio(1);
#pragma unroll
    for (int mi = 0; mi < 4; ++mi)
#pragma unroll
      for (int ni = 0; ni < 4; ++ni)
        acc[mi][ni] = __builtin_amdgcn_mfma_f32_16x16x32_bf16(
            af[mi], bf[ni], acc[mi][ni], 0, 0, 0);
    __builtin_amdgcn_s_setprio(0);
    asm volatile("s_barrier" ::: "memory");

    // ---- q1: kk=0, mi 4-7 ----
#pragma unroll
    for (int i = 0; i < 4; ++i) af[i] = *(const bf16x8*)(pA + 2048 + i * 512);
    if (t + 2 < NTILES) stgB(t + 2, 0);
    asm volatile("s_barrier" ::: "memory");
    asm volatile("s_waitcnt lgkmcnt(0)" ::: "memory");
    __builtin_amdgcn_s_setprio(1);
#pragma unroll
    for (int mi = 0; mi < 4; ++mi)
#pragma unroll
      for (int ni = 0; ni < 4; ++ni)
        acc[4 + mi][ni] = __builtin_amdgcn_mfma_f32_16x16x32_bf16(
            af[mi], bf[ni], acc[4 + mi][ni], 0, 0, 0);
    __builtin_amdgcn_s_setprio(0);
    asm volatile("s_barrier" ::: "memory");

    // ---- q2: kk=1, mi 0-3 ----
#pragma unroll
    for (int i = 0; i < 4; ++i) bf[i] = *(const bf16x8*)(pB + 8192 + i * 512);
#pragma unroll
    for (int i = 0; i < 4; ++i) af[i] = *(const bf16x8*)(pA + 8192 + i * 512);
    if (t + 2 < NTILES) stgA(t + 2, 0);
    asm volatile("s_barrier" ::: "memory");
    asm volatile("s_waitcnt lgkmcnt(0)" ::: "memory");
    __builtin_amdgcn_s_setprio(1);
#pragma unroll
    for (int mi = 0; mi < 4; ++mi)
#pragma unroll
      for (int ni = 0; ni < 4; ++ni)
        acc[mi][ni] = __builtin_amdgcn_mfma_f32_16x16x32_bf16(
            af[mi], bf[ni], acc[mi][ni], 0, 0, 0);
    __builtin_amdgcn_s_setprio(0);
    asm volatile("s_barrier" ::: "memory");

    // ---- q3: kk=1, mi 4-7 ----
#pragma unroll
    for (int i = 0; i < 4; ++i) af[i] = *(const bf16x8*)(pA + 8192 + 2048 + i * 512);
    if (t + 2 < NTILES) stgB(t + 2, 1);
    if (t < NTILES - 2) asm volatile("s_waitcnt vmcnt(6)" ::: "memory");
    else                asm volatile("s_waitcnt vmcnt(0)" ::: "memory");
    asm volatile("s_barrier" ::: "memory");
    asm volatile("s_waitcnt lgkmcnt(0)" ::: "memory");
    __builtin_amdgcn_s_setprio(1);
#pragma unroll
    for (int mi = 0; mi < 4; ++mi)
#pragma unroll
      for (int ni = 0; ni < 4; ++ni)
        acc[4 + mi][ni] = __builtin_amdgcn_mfma_f32_16x16x32_bf16(
            af[mi], bf[ni], acc[4 + mi][ni], 0, 0, 0);
    __builtin_amdgcn_s_setprio(0);
    asm volatile("s_barrier" ::: "memory");
  }

  int orow = bm * 256 + wr * 128 + ((lane >> 4) << 2);
  int ocol = bn * 256 + wc * 64 + lr;
#pragma unroll
  for (int mi = 0; mi < 8; ++mi)
#pragma unroll
    for (int ni = 0; ni < 4; ++ni)
#pragma unroll
      for (int j = 0; j < 4; ++j)
        out[(size_t)(orow + mi * 16 + j) * COUT + (ocol + ni * 16)] = acc[mi][ni][j];
}

// ---- K4: in-place epilogue on dot rows: poincare_linear tail + project ----
__global__ __launch_bounds__(128) void k_epi(float* __restrict__ out,
                                             const float* __restrict__ nsq,
                                             const float* __restrict__ wg,
                                             const float* __restrict__ chv,
                                             const float* __restrict__ shv) {
  int m = blockIdx.x;
  int tid = threadIdx.x;                 // 128
  int lane = tid & 63, wv_ = tid >> 6;
  float un2 = nsq[m] + nsq[m + 16] + nsq[m + 32];
  float un = sqrtf(un2);
  float unc = fmaxf(un, 1e-15f);
  float e2 = fast_exp2(unc * (2.f * LOG2E));
  float th = (e2 - 1.f) * fast_rcp(e2 + 1.f);
  float sxp = th * fast_rcp(unc);        // expmap0 scale (RC=1)
  float cx2 = sxp * sxp * un2;           // ||rcx||^2
  float iden = fast_rcp(fmaxf(1.f - cx2, 1e-15f));

  float4 dv = ((const float4*)(out + (size_t)m * COUT))[tid];
  float4 gv = ((const float4*)wg)[tid];
  float4 cv = ((const float4*)chv)[tid];
  float4 sv = ((const float4*)shv)[tid];
  float dot[4] = {dv.x, dv.y, dv.z, dv.w};
  float gvr[4] = {gv.x, gv.y, gv.z, gv.w};
  float chr[4] = {cv.x, cv.y, cv.z, cv.w};
  float shr[4] = {sv.x, sv.y, sv.z, sv.w};
  float y[4];
  float opc = 1.f + cx2;
#pragma unroll
  for (int e = 0; e < 4; ++e) {
    float num = 2.f * (sxp * dot[e]) * chr[e] - opc * shr[e];
    float z = num * iden;
    float w = z + sqrtf(fmaf(z, z, 1.f));
    float l = fast_log2(w);
    float E = fast_exp2((2.f * gvr[e]) * l);
    y[e] = 0.5f * (E - fast_rcp(E));
  }
  float ssl = y[0]*y[0] + y[1]*y[1] + y[2]*y[2] + y[3]*y[3];
#pragma unroll
  for (int d = 1; d < 64; d <<= 1) ssl += __shfl_xor(ssl, d);
  __shared__ float red[2];
  if (lane == 0) red[wv_] = ssl;
  __syncthreads();
  float ss = red[0] + red[1];
  float denom = 1.f + sqrtf(1.f + ss);
  float idn = 1.f / denom;
  float nrm = fmaxf(sqrtf(ss) * idn, 1e-15f);
  float maxn = 1.0f - 4e-3f;
  float scale = (nrm > maxn) ? (maxn / nrm) : 1.f;
  scale *= idn;
  float4 ov;
  ov.x = y[0] * scale;
  ov.y = y[1] * scale;
  ov.z = y[2] * scale;
  ov.w = y[3] * scale;
  ((float4*)(out + (size_t)m * COUT))[tid] = ov;
}

extern "C" void kernel_launch(void* const* d_in, const int* in_sizes, int n_in,
                              void* d_out, int out_size, void* d_ws, size_t ws_size,
                              hipStream_t stream) {
  const float* x    = (const float*)d_in[0];
  const float* wg   = (const float*)d_in[1];
  const float* wv   = (const float*)d_in[2];
  const float* bias = (const float*)d_in[3];
  float* out = (float*)d_out;

  char* ws = (char*)d_ws;
  u16*   U    = (u16*)(ws);                    // 2050*16*512 bf16 = 33,587,200 B
  float* NSQ  = (float*)(ws + 33587200);       // 32800 f32      =    131,200 B
  u16*   WT   = (u16*)(ws + 33718400);         // 512*1536 bf16  =  1,572,864 B
  float* INVN = (float*)(ws + 35291264);       // 512 f32
  float* CH   = (float*)(ws + 35293312);       // 512 f32
  float* SH   = (float*)(ws + 35295360);       // 512 f32
  float* PART = (float*)(ws + 35297408);       // 24*512 f32 = 49,152 B

  double lb = (lgamma(768.0) + lgamma(0.5) - lgamma(768.5))
            - (lgamma(256.0) + lgamma(0.5) - lgamma(256.5));
  float beta_ratio = (float)exp(lb);           // beta(768,.5)/beta(256,.5)

  k_colnorm<<<dim3(COUT / 256, KIN / 64), 256, 0, stream>>>(wv, PART);
  k_fin<<<COUT / 256, 256, 0, stream>>>(PART, INVN);
  k_chsh<<<COUT / 128, 128, 0, stream>>>(bias, CH, SH);
  k_wt<<<dim3(KIN / 64, COUT / 64), 256, 0, stream>>>(wv, INVN, WT);
  k_logmap<<<UROWS, 64, 0, stream>>>(x, U, NSQ, beta_ratio);
  k_gemm<<<(NROWS / 256) * (COUT / 256), 512, 0, stream>>>(U, WT, out);
  k_epi<<<NROWS, 128, 0, stream>>>(out, NSQ, wg, CH, SH);
}

// Round 10
// 115.603 us; speedup vs baseline: 1.0428x; 1.0212x over previous
//
#include <hip/hip_runtime.h>
#include <cstdint>
#include <cmath>

typedef unsigned short u16;
typedef short bf16x8 __attribute__((ext_vector_type(8)));
typedef float f32x4 __attribute__((ext_vector_type(4)));

#define T_DIM 2048
#define B_DIM 16
#define CIN 512
#define COUT 512
#define KIN 1536
#define NROWS (T_DIM * B_DIM)        /* 32768 */
#define UROWS ((T_DIM + 2) * B_DIM)  /* 32800 */

#define NTILES 24                    /* K-tiles of 64 */

#define LOG2E 1.44269504088896f
#define LN2   0.69314718055995f

__device__ __forceinline__ float fast_exp2(float x) {
#if __has_builtin(__builtin_amdgcn_exp2f)
  return __builtin_amdgcn_exp2f(x);
#else
  return __builtin_exp2f(x);
#endif
}
__device__ __forceinline__ float fast_log2(float x) {
#if __has_builtin(__builtin_amdgcn_logf)
  return __builtin_amdgcn_logf(x);   // v_log_f32 = log2(x)
#else
  return __builtin_log2f(x);
#endif
}
__device__ __forceinline__ float fast_rcp(float x) {
  return __builtin_amdgcn_rcpf(x);
}

__device__ __forceinline__ u16 f2bf(float f) {
  unsigned u = __builtin_bit_cast(unsigned, f);
  u = (u + 0x7FFFu + ((u >> 16) & 1u)) >> 16;   // RNE
  return (u16)u;
}

typedef __attribute__((address_space(3))) unsigned int as3u32;
typedef __attribute__((address_space(1))) unsigned int as1u32;

// async global->LDS, 16B per lane; lds must be the wave-uniform base.
__device__ __forceinline__ void gload16(const u16* g, const u16* lds) {
#if __has_builtin(__builtin_amdgcn_global_load_lds)
  __builtin_amdgcn_global_load_lds((as1u32*)(uintptr_t)g,
                                   (as3u32*)(unsigned)(uintptr_t)lds, 16, 0, 0);
#else
  unsigned lane = __lane_id();
  ((uint4*)lds)[lane] = *(const uint4*)g;
#endif
}

// ---- K0a: partial column sumsq of weight_v [KIN, COUT], coalesced ----
__global__ __launch_bounds__(256) void k_colnorm(const float* __restrict__ wv,
                                                 float* __restrict__ partial) {
  int o = blockIdx.x * 256 + threadIdx.x;
  int r0 = blockIdx.y * 64;
  float s = 0.f;
#pragma unroll 8
  for (int r = 0; r < 64; ++r) {
    float v = wv[(size_t)(r0 + r) * COUT + o];
    s += v * v;
  }
  partial[(size_t)blockIdx.y * COUT + o] = s;
}

// ---- K0c: finalize invn + per-channel cosh/sinh of 2*bias ----
__global__ __launch_bounds__(256) void k_fin(const float* __restrict__ partial,
                                             const float* __restrict__ bias,
                                             float* __restrict__ invn,
                                             float* __restrict__ ch,
                                             float* __restrict__ sh) {
  int o = blockIdx.x * 256 + threadIdx.x;
  float s = 0.f;
#pragma unroll
  for (int j = 0; j < KIN / 64; ++j) s += partial[(size_t)j * COUT + o];
  invn[o] = 1.f / fmaxf(sqrtf(s), 1e-15f);
  float d = 2.f * bias[o];
  float e = fast_exp2(d * LOG2E);
  float ie = fast_rcp(e);
  ch[o] = 0.5f * (e + ie);
  sh[o] = 0.5f * (e - ie);
}

// ---- K1: W^T bf16: wt[o][i] = wv[i][o] * invn[o] ----
__global__ void k_wt(const float* __restrict__ wv, const float* __restrict__ invn,
                     u16* __restrict__ wt) {
  __shared__ float tile[64][65];
  int i0 = blockIdx.x * 64;
  int o0 = blockIdx.y * 64;
  int tx = threadIdx.x & 63, ty = threadIdx.x >> 6;  // 256 thr
  for (int r = ty; r < 64; r += 4)
    tile[r][tx] = wv[(size_t)(i0 + r) * COUT + o0 + tx];
  __syncthreads();
  for (int r = ty; r < 64; r += 4) {
    float inv = invn[o0 + r];
    wt[(size_t)(o0 + r) * KIN + i0 + tx] = f2bf(tile[tx][r] * inv);
  }
}

// ---- K2: u = logmap0(x)*BETA_RATIO -> bf16 [UROWS,512]; nsq fp32 per row ----
__global__ void k_logmap(const float* __restrict__ x, u16* __restrict__ U,
                         float* __restrict__ nsq, float beta_ratio) {
  int row = blockIdx.x;        // 0..32799 = t_pad*16 + b
  int t = row >> 4;
  int lane = threadIdx.x;      // 64
  uint4* urow = (uint4*)(U + (size_t)row * CIN);
  if (t == 0 || t == T_DIM + 1) {
    uint4 z; z.x = z.y = z.z = z.w = 0u;
    urow[lane] = z;
    if (lane == 0) nsq[row] = 0.f;
    return;
  }
  const float4* xr = (const float4*)(x + (size_t)(row - 16) * CIN);
  float4 a = xr[lane * 2];
  float4 b = xr[lane * 2 + 1];
  float s = a.x*a.x + a.y*a.y + a.z*a.z + a.w*a.w
          + b.x*b.x + b.y*b.y + b.z*b.z + b.w*b.w;
#pragma unroll
  for (int d = 1; d < 64; d <<= 1) s += __shfl_xor(s, d);
  float r = sqrtf(s);
  float yn = fmaxf(r, 1e-15f);
  float arg = fminf(yn, 1.0f - 1e-7f);
  float at = 0.5f * LN2 * fast_log2((1.f + arg) * fast_rcp(1.f - arg));
  float f = at / yn * beta_ratio;
  union { u16 h[8]; uint4 v; } pk;
  pk.h[0] = f2bf(a.x * f); pk.h[1] = f2bf(a.y * f);
  pk.h[2] = f2bf(a.z * f); pk.h[3] = f2bf(a.w * f);
  pk.h[4] = f2bf(b.x * f); pk.h[5] = f2bf(b.y * f);
  pk.h[6] = f2bf(b.z * f); pk.h[7] = f2bf(b.w * f);
  urow[lane] = pk.v;
  if (lane == 0) nsq[row] = s * f * f;
}

// ---- K3: GEMM, 8-phase schedule + one-phase-ahead fragment prefetch ----
// 256x256 tile, BK=64 as 2 K-halves, LDS [buf][khalf][256][32]u16 (128 KiB).
// 8 waves (2M x 4N), wave 128x64, acc[8][4]. Per K-tile 4 quadrant-phases;
// each phase ISSUES the ds_reads for the NEXT phase's fragments (alternate
// af/bf register sets), so the LDS serve overlaps the current MFMA cluster
// and the compiler's counted lgkm wait before each MFMA is ~free.
// Stage map per tile t: q0->A1(t+1), q1->B0(t+2), q2->A0(t+2), q3->B1(t+2);
// vmcnt(6) once per tile. Swizzle: chunk ^= (row>>1)&3 (2-way = free);
// pre-swizzled global source, linear gload dests.
__global__ __launch_bounds__(512, 2) void k_gemm(const u16* __restrict__ U,
                                                 const u16* __restrict__ WT,
                                                 float* __restrict__ out) {
  __shared__ u16 lA[2][2][8192];   // [buf][khalf][256*32]
  __shared__ u16 lB[2][2][8192];
  int bid = blockIdx.x;
  // XCD-contiguous: 32 consecutive wgids per XCD; bn-pairs adjacent.
  int wgid = (bid & 7) * 32 + (bid >> 3);
  int bm = wgid >> 1, bn = wgid & 1;
  int tid = threadIdx.x;
  int lane = tid & 63;
  int wid = tid >> 6;
  int wr = wid >> 2, wc = wid & 3;      // wave tile: 128 rows x 64 cols
  int lr = lane & 15;
  int srow = tid >> 2;                  // staging row (0..127), +128 for 2nd
  int sc = (tid & 3) ^ ((tid >> 3) & 3);        // pre-swizzled src chunk
  int cSwz = ((lane >> 4) ^ ((lr >> 1) & 3)) << 3;  // frag read chunk (u16)

  f32x4 acc[8][4] = {};

  auto stgA = [&](int tt, int h) {
    int ks32 = tt * 2 + h;
    int seg = ks32 >> 4;                 // conv tap 0..2
    int c0 = (ks32 & 15) << 5;           // col offset within tap
    const u16* g = U + (size_t)(bm * 256 + seg * 16 + srow) * 512 + c0 + sc * 8;
    const u16* d = &lA[tt & 1][h][wid * 512];
    gload16(g, d);
    gload16(g + (size_t)128 * 512, d + 4096);
  };
  auto stgB = [&](int tt, int h) {
    int ks32 = tt * 2 + h;
    const u16* g = WT + (size_t)(bn * 256 + srow) * KIN + ks32 * 32 + sc * 8;
    const u16* d = &lB[tt & 1][h][wid * 512];
    gload16(g, d);
    gload16(g + (size_t)128 * KIN, d + 4096);
  };

  // prologue: tile0 complete + tile1 {B0,A0,B1} = 7 half-tiles, 14 loads
  stgA(0, 0); stgB(0, 0); stgA(0, 1); stgB(0, 1);
  stgB(1, 0); stgA(1, 0); stgB(1, 1);
  asm volatile("s_waitcnt vmcnt(6)" ::: "memory");   // tile0 landed
  asm volatile("s_barrier" ::: "memory");

  bf16x8 afA[4], afB[4], bfE[4], bfO[4];
  {
    const u16* pA0 = &lA[0][0][(wr * 128 + lr) * 32 + cSwz];
    const u16* pB0 = &lB[0][0][(wc * 64 + lr) * 32 + cSwz];
#pragma unroll
    for (int i = 0; i < 4; ++i) afA[i] = *(const bf16x8*)(pA0 + i * 512);
#pragma unroll
    for (int i = 0; i < 4; ++i) bfE[i] = *(const bf16x8*)(pB0 + i * 512);
  }

  for (int t = 0; t < NTILES; ++t) {
    int b = t & 1;
    const u16* pA = &lA[b][0][(wr * 128 + lr) * 32 + cSwz];
    const u16* pB = &lB[b][0][(wc * 64 + lr) * 32 + cSwz];
    const u16* pAn = &lA[b ^ 1][0][(wr * 128 + lr) * 32 + cSwz];
    const u16* pBn = &lB[b ^ 1][0][(wc * 64 + lr) * 32 + cSwz];

    // ---- q0: MFMA(afA, bfE) -> acc[0-3]; prefetch afB = A-hi kk0 ----
#pragma unroll
    for (int i = 0; i < 4; ++i) afB[i] = *(const bf16x8*)(pA + 2048 + i * 512);
    if (t + 1 < NTILES) stgA(t + 1, 1);
    asm volatile("s_barrier" ::: "memory");
    __builtin_amdgcn_s_setprio(1);
#pragma unroll
    for (int mi = 0; mi < 4; ++mi)
#pragma unroll
      for (int ni = 0; ni < 4; ++ni)
        acc[mi][ni] = __builtin_amdgcn_mfma_f32_16x16x32_bf16(
            afA[mi], bfE[ni], acc[mi][ni], 0, 0, 0);
    __builtin_amdgcn_s_setprio(0);
    asm volatile("s_barrier" ::: "memory");

    // ---- q1: MFMA(afB, bfE) -> acc[4-7]; prefetch afA = A-lo kk1, bfO ----
#pragma unroll
    for (int i = 0; i < 4; ++i) afA[i] = *(const bf16x8*)(pA + 8192 + i * 512);
#pragma unroll
    for (int i = 0; i < 4; ++i) bfO[i] = *(const bf16x8*)(pB + 8192 + i * 512);
    if (t + 2 < NTILES) stgB(t + 2, 0);
    asm volatile("s_barrier" ::: "memory");
    __builtin_amdgcn_s_setprio(1);
#pragma unroll
    for (int mi = 0; mi < 4; ++mi)
#pragma unroll
      for (int ni = 0; ni < 4; ++ni)
        acc[4 + mi][ni] = __builtin_amdgcn_mfma_f32_16x16x32_bf16(
            afB[mi], bfE[ni], acc[4 + mi][ni], 0, 0, 0);
    __builtin_amdgcn_s_setprio(0);
    asm volatile("s_barrier" ::: "memory");

    // ---- q2: MFMA(afA, bfO) -> acc[0-3]; prefetch afB = A-hi kk1 ----
#pragma unroll
    for (int i = 0; i < 4; ++i)
      afB[i] = *(const bf16x8*)(pA + 8192 + 2048 + i * 512);
    if (t + 2 < NTILES) stgA(t + 2, 0);
    asm volatile("s_barrier" ::: "memory");
    __builtin_amdgcn_s_setprio(1);
#pragma unroll
    for (int mi = 0; mi < 4; ++mi)
#pragma unroll
      for (int ni = 0; ni < 4; ++ni)
        acc[mi][ni] = __builtin_amdgcn_mfma_f32_16x16x32_bf16(
            afA[mi], bfO[ni], acc[mi][ni], 0, 0, 0);
    __builtin_amdgcn_s_setprio(0);
    asm volatile("s_barrier" ::: "memory");

    // ---- q3: MFMA(afB, bfO) -> acc[4-7]; prefetch afA/bfE for tile t+1 ----
    if (t + 1 < NTILES) {
#pragma unroll
      for (int i = 0; i < 4; ++i) afA[i] = *(const bf16x8*)(pAn + i * 512);
#pragma unroll
      for (int i = 0; i < 4; ++i) bfE[i] = *(const bf16x8*)(pBn + i * 512);
    }
    if (t + 2 < NTILES) stgB(t + 2, 1);
    if (t < NTILES - 2) asm volatile("s_waitcnt vmcnt(6)" ::: "memory");
    else                asm volatile("s_waitcnt vmcnt(0)" ::: "memory");
    asm volatile("s_barrier" ::: "memory");
    __builtin_amdgcn_s_setprio(1);
#pragma unroll
    for (int mi = 0; mi < 4; ++mi)
#pragma unroll
      for (int ni = 0; ni < 4; ++ni)
        acc[4 + mi][ni] = __builtin_amdgcn_mfma_f32_16x16x32_bf16(
            afB[mi], bfO[ni], acc[4 + mi][ni], 0, 0, 0);
    __builtin_amdgcn_s_setprio(0);
    asm volatile("s_barrier" ::: "memory");
  }

  int orow = bm * 256 + wr * 128 + ((lane >> 4) << 2);
  int ocol = bn * 256 + wc * 64 + lr;
#pragma unroll
  for (int mi = 0; mi < 8; ++mi)
#pragma unroll
    for (int ni = 0; ni < 4; ++ni)
#pragma unroll
      for (int j = 0; j < 4; ++j)
        out[(size_t)(orow + mi * 16 + j) * COUT + (ocol + ni * 16)] = acc[mi][ni][j];
}

// ---- K4: in-place epilogue on dot rows: poincare_linear tail + project ----
__global__ __launch_bounds__(128) void k_epi(float* __restrict__ out,
                                             const float* __restrict__ nsq,
                                             const float* __restrict__ wg,
                                             const float* __restrict__ chv,
                                             const float* __restrict__ shv) {
  int m = blockIdx.x;
  int tid = threadIdx.x;                 // 128
  int lane = tid & 63, wv_ = tid >> 6;
  float un2 = nsq[m] + nsq[m + 16] + nsq[m + 32];
  float un = sqrtf(un2);
  float unc = fmaxf(un, 1e-15f);
  float e2 = fast_exp2(unc * (2.f * LOG2E));
  float th = (e2 - 1.f) * fast_rcp(e2 + 1.f);
  float sxp = th * fast_rcp(unc);        // expmap0 scale (RC=1)
  float cx2 = sxp * sxp * un2;           // ||rcx||^2
  float iden = fast_rcp(fmaxf(1.f - cx2, 1e-15f));

  float4 dv = ((const float4*)(out + (size_t)m * COUT))[tid];
  float4 gv = ((const float4*)wg)[tid];
  float4 cv = ((const float4*)chv)[tid];
  float4 sv = ((const float4*)shv)[tid];
  float dot[4] = {dv.x, dv.y, dv.z, dv.w};
  float gvr[4] = {gv.x, gv.y, gv.z, gv.w};
  float chr[4] = {cv.x, cv.y, cv.z, cv.w};
  float shr[4] = {sv.x, sv.y, sv.z, sv.w};
  float y[4];
  float opc = 1.f + cx2;
#pragma unroll
  for (int e = 0; e < 4; ++e) {
    float num = 2.f * (sxp * dot[e]) * chr[e] - opc * shr[e];
    float z = num * iden;
    float w = z + sqrtf(fmaf(z, z, 1.f));
    float l = fast_log2(w);
    float E = fast_exp2((2.f * gvr[e]) * l);
    y[e] = 0.5f * (E - fast_rcp(E));
  }
  float ssl = y[0]*y[0] + y[1]*y[1] + y[2]*y[2] + y[3]*y[3];
#pragma unroll
  for (int d = 1; d < 64; d <<= 1) ssl += __shfl_xor(ssl, d);
  __shared__ float red[2];
  if (lane == 0) red[wv_] = ssl;
  __syncthreads();
  float ss = red[0] + red[1];
  float denom = 1.f + sqrtf(1.f + ss);
  float idn = 1.f / denom;
  float nrm = fmaxf(sqrtf(ss) * idn, 1e-15f);
  float maxn = 1.0f - 4e-3f;
  float scale = (nrm > maxn) ? (maxn / nrm) : 1.f;
  scale *= idn;
  float4 ov;
  ov.x = y[0] * scale;
  ov.y = y[1] * scale;
  ov.z = y[2] * scale;
  ov.w = y[3] * scale;
  ((float4*)(out + (size_t)m * COUT))[tid] = ov;
}

extern "C" void kernel_launch(void* const* d_in, const int* in_sizes, int n_in,
                              void* d_out, int out_size, void* d_ws, size_t ws_size,
                              hipStream_t stream) {
  const float* x    = (const float*)d_in[0];
  const float* wg   = (const float*)d_in[1];
  const float* wv   = (const float*)d_in[2];
  const float* bias = (const float*)d_in[3];
  float* out = (float*)d_out;

  char* ws = (char*)d_ws;
  u16*   U    = (u16*)(ws);                    // 2050*16*512 bf16 = 33,587,200 B
  float* NSQ  = (float*)(ws + 33587200);       // 32800 f32      =    131,200 B
  u16*   WT   = (u16*)(ws + 33718400);         // 512*1536 bf16  =  1,572,864 B
  float* INVN = (float*)(ws + 35291264);       // 512 f32
  float* CH   = (float*)(ws + 35293312);       // 512 f32
  float* SH   = (float*)(ws + 35295360);       // 512 f32
  float* PART = (float*)(ws + 35297408);       // 24*512 f32 = 49,152 B

  double lb = (lgamma(768.0) + lgamma(0.5) - lgamma(768.5))
            - (lgamma(256.0) + lgamma(0.5) - lgamma(256.5));
  float beta_ratio = (float)exp(lb);           // beta(768,.5)/beta(256,.5)

  k_colnorm<<<dim3(COUT / 256, KIN / 64), 256, 0, stream>>>(wv, PART);
  k_fin<<<COUT / 256, 256, 0, stream>>>(PART, bias, INVN, CH, SH);
  k_wt<<<dim3(KIN / 64, COUT / 64), 256, 0, stream>>>(wv, INVN, WT);
  k_logmap<<<UROWS, 64, 0, stream>>>(x, U, NSQ, beta_ratio);
  k_gemm<<<(NROWS / 256) * (COUT / 256), 512, 0, stream>>>(U, WT, out);
  k_epi<<<NROWS, 128, 0, stream>>>(out, NSQ, wg, CH, SH);
}

// Round 11
// 105.003 us; speedup vs baseline: 1.1481x; 1.1010x over previous
//
#include <hip/hip_runtime.h>
#include <cstdint>
#include <cmath>

typedef unsigned short u16;
typedef short bf16x8 __attribute__((ext_vector_type(8)));
typedef float f32x4 __attribute__((ext_vector_type(4)));

#define T_DIM 2048
#define B_DIM 16
#define CIN 512
#define COUT 512
#define KIN 1536
#define NROWS (T_DIM * B_DIM)        /* 32768 */
#define UROWS ((T_DIM + 2) * B_DIM)  /* 32800 */

#define NS 48                        /* K-steps of 32 */

#define LOG2E 1.44269504088896f
#define LN2   0.69314718055995f

__device__ __forceinline__ float fast_exp2(float x) {
#if __has_builtin(__builtin_amdgcn_exp2f)
  return __builtin_amdgcn_exp2f(x);
#else
  return __builtin_exp2f(x);
#endif
}
__device__ __forceinline__ float fast_log2(float x) {
#if __has_builtin(__builtin_amdgcn_logf)
  return __builtin_amdgcn_logf(x);   // v_log_f32 = log2(x)
#else
  return __builtin_log2f(x);
#endif
}
__device__ __forceinline__ float fast_rcp(float x) {
  return __builtin_amdgcn_rcpf(x);
}

__device__ __forceinline__ u16 f2bf(float f) {
  unsigned u = __builtin_bit_cast(unsigned, f);
  u = (u + 0x7FFFu + ((u >> 16) & 1u)) >> 16;   // RNE
  return (u16)u;
}

typedef __attribute__((address_space(3))) unsigned int as3u32;
typedef __attribute__((address_space(1))) unsigned int as1u32;

// async global->LDS, 16B per lane; lds must be the wave-uniform base.
__device__ __forceinline__ void gload16(const u16* g, const u16* lds) {
#if __has_builtin(__builtin_amdgcn_global_load_lds)
  __builtin_amdgcn_global_load_lds((as1u32*)(uintptr_t)g,
                                   (as3u32*)(unsigned)(uintptr_t)lds, 16, 0, 0);
#else
  unsigned lane = __lane_id();
  ((uint4*)lds)[lane] = *(const uint4*)g;
#endif
}

// ---- K0a: partial column sumsq of weight_v [KIN, COUT], coalesced ----
__global__ __launch_bounds__(256) void k_colnorm(const float* __restrict__ wv,
                                                 float* __restrict__ partial) {
  int o = blockIdx.x * 256 + threadIdx.x;
  int r0 = blockIdx.y * 64;
  float s = 0.f;
#pragma unroll 8
  for (int r = 0; r < 64; ++r) {
    float v = wv[(size_t)(r0 + r) * COUT + o];
    s += v * v;
  }
  partial[(size_t)blockIdx.y * COUT + o] = s;
}

// ---- K0c: finalize invn + per-channel cosh/sinh of 2*bias ----
__global__ __launch_bounds__(256) void k_fin(const float* __restrict__ partial,
                                             const float* __restrict__ bias,
                                             float* __restrict__ invn,
                                             float* __restrict__ ch,
                                             float* __restrict__ sh) {
  int o = blockIdx.x * 256 + threadIdx.x;
  float s = 0.f;
#pragma unroll
  for (int j = 0; j < KIN / 64; ++j) s += partial[(size_t)j * COUT + o];
  invn[o] = 1.f / fmaxf(sqrtf(s), 1e-15f);
  float d = 2.f * bias[o];
  float e = fast_exp2(d * LOG2E);
  float ie = fast_rcp(e);
  ch[o] = 0.5f * (e + ie);
  sh[o] = 0.5f * (e - ie);
}

// ---- K1: W^T bf16: wt[o][i] = wv[i][o] * invn[o] ----
__global__ void k_wt(const float* __restrict__ wv, const float* __restrict__ invn,
                     u16* __restrict__ wt) {
  __shared__ float tile[64][65];
  int i0 = blockIdx.x * 64;
  int o0 = blockIdx.y * 64;
  int tx = threadIdx.x & 63, ty = threadIdx.x >> 6;  // 256 thr
  for (int r = ty; r < 64; r += 4)
    tile[r][tx] = wv[(size_t)(i0 + r) * COUT + o0 + tx];
  __syncthreads();
  for (int r = ty; r < 64; r += 4) {
    float inv = invn[o0 + r];
    wt[(size_t)(o0 + r) * KIN + i0 + tx] = f2bf(tile[tx][r] * inv);
  }
}

// ---- K2: u = logmap0(x)*BETA_RATIO -> bf16 [UROWS,512]; nsq fp32 per row ----
__global__ void k_logmap(const float* __restrict__ x, u16* __restrict__ U,
                         float* __restrict__ nsq, float beta_ratio) {
  int row = blockIdx.x;        // 0..32799 = t_pad*16 + b
  int t = row >> 4;
  int lane = threadIdx.x;      // 64
  uint4* urow = (uint4*)(U + (size_t)row * CIN);
  if (t == 0 || t == T_DIM + 1) {
    uint4 z; z.x = z.y = z.z = z.w = 0u;
    urow[lane] = z;
    if (lane == 0) nsq[row] = 0.f;
    return;
  }
  const float4* xr = (const float4*)(x + (size_t)(row - 16) * CIN);
  float4 a = xr[lane * 2];
  float4 b = xr[lane * 2 + 1];
  float s = a.x*a.x + a.y*a.y + a.z*a.z + a.w*a.w
          + b.x*b.x + b.y*b.y + b.z*b.z + b.w*b.w;
#pragma unroll
  for (int d = 1; d < 64; d <<= 1) s += __shfl_xor(s, d);
  float r = sqrtf(s);
  float yn = fmaxf(r, 1e-15f);
  float arg = fminf(yn, 1.0f - 1e-7f);
  float at = 0.5f * LN2 * fast_log2((1.f + arg) * fast_rcp(1.f - arg));
  float f = at / yn * beta_ratio;
  union { u16 h[8]; uint4 v; } pk;
  pk.h[0] = f2bf(a.x * f); pk.h[1] = f2bf(a.y * f);
  pk.h[2] = f2bf(a.z * f); pk.h[3] = f2bf(a.w * f);
  pk.h[4] = f2bf(b.x * f); pk.h[5] = f2bf(b.y * f);
  pk.h[6] = f2bf(b.z * f); pk.h[7] = f2bf(b.w * f);
  urow[lane] = pk.v;
  if (lane == 0) nsq[row] = s * f * f;
}

// ---- K3: fused GEMM + poincare epilogue ----
// Block = 128 rows x 512 cols (full output rows -> in-block projection).
// BK=32, 3-deep LDS ring (A 3x8KB + B 3x32KB = 120 KiB), 2-tile lookahead,
// counted vmcnt(5) per tile (never 0 until tail), ONE barrier per tile
// (WAR safety: stage(t+2) writes buf((t+2)%3)=buf((t-1)%3) whose readers
// lgkm-fenced before the t-1/t barrier). 8 waves (2M x 4N), wave 64x128,
// acc[4][8]. Swizzle: phys chunk = c ^ ((row>>1)&3) in 64B rows (2-way
// aliasing = free); pre-swizzled global src, linear gload dests.
// Epilogue: y = sinh(2g*asinh(z)) via hw log2/exp2; per-row sum(y^2) via
// 16-lane shfl + LDS scratch (reuses lA); project; store final out.
__global__ __launch_bounds__(512, 2) void k_gemm(const u16* __restrict__ U,
                                                 const u16* __restrict__ WT,
                                                 const float* __restrict__ nsq,
                                                 const float* __restrict__ wg,
                                                 const float* __restrict__ chv,
                                                 const float* __restrict__ shv,
                                                 float* __restrict__ out) {
  __shared__ u16 lA[3][128 * 32];   // 3 x 8 KiB
  __shared__ u16 lB[3][512 * 32];   // 3 x 32 KiB
  int bm = blockIdx.x;              // 256 blocks, 128 rows each
  int tid = threadIdx.x;
  int lane = tid & 63;
  int wid = tid >> 6;
  int wr = wid >> 2, wc = wid & 3;      // wave tile: 64 rows x 128 cols
  int lr = lane & 15;
  int sc = (tid & 3) ^ ((tid >> 3) & 3);            // pre-swizzled src chunk
  int cSwz = ((lane >> 4) ^ ((lr >> 1) & 3)) << 3;  // frag read chunk (u16)

  f32x4 acc[4][8] = {};

  auto stgA = [&](int t, int p) {
    int seg = t >> 4;                    // conv tap 0..2
    int c0 = (t & 15) << 5;              // col offset within tap (u16)
    gload16(U + (size_t)(bm * 128 + seg * 16 + (tid >> 2)) * 512 + c0 + sc * 8,
            &lA[p][wid * 512]);
  };
  auto stgB = [&](int t, int p) {
#pragma unroll
    for (int r = 0; r < 4; ++r)
      gload16(WT + (size_t)(r * 128 + (tid >> 2)) * KIN + t * 32 + sc * 8,
              &lB[p][r * 4096 + wid * 512]);
  };

  // prologue: stage tiles 0,1 (5 loads each)
  stgA(0, 0); stgB(0, 0);
  stgA(1, 1); stgB(1, 1);
  asm volatile("s_waitcnt vmcnt(5)" ::: "memory");   // tile0 landed
  asm volatile("s_barrier" ::: "memory");

  for (int tt = 0; tt < 16; ++tt) {
#pragma unroll
    for (int u = 0; u < 3; ++u) {
      int t = tt * 3 + u;
      int b = u;                        // t % 3
      int p = (u + 2) % 3;
      if (t + 2 < NS) { stgA(t + 2, p); stgB(t + 2, p); }
      const u16* pA = &lA[b][(wr * 64 + lr) * 32 + cSwz];
      const u16* pB = &lB[b][(wc * 128 + lr) * 32 + cSwz];
      bf16x8 af[4], bf[8];
#pragma unroll
      for (int i = 0; i < 4; ++i) af[i] = *(const bf16x8*)(pA + i * 512);
#pragma unroll
      for (int i = 0; i < 8; ++i) bf[i] = *(const bf16x8*)(pB + i * 512);
      __builtin_amdgcn_s_setprio(1);
#pragma unroll
      for (int mi = 0; mi < 4; ++mi)
#pragma unroll
        for (int ni = 0; ni < 8; ++ni)
          acc[mi][ni] = __builtin_amdgcn_mfma_f32_16x16x32_bf16(
              af[mi], bf[ni], acc[mi][ni], 0, 0, 0);
      __builtin_amdgcn_s_setprio(0);
      asm volatile("s_waitcnt lgkmcnt(0)" ::: "memory");  // buf b reads done
      if (t < NS - 2)       asm volatile("s_waitcnt vmcnt(5)" ::: "memory");
      else if (t == NS - 2) asm volatile("s_waitcnt vmcnt(0)" ::: "memory");
      asm volatile("s_barrier" ::: "memory");
    }
  }

  // ---- fused epilogue: all K-loop LDS reads fenced -> reuse lA ----
  float* scr = (float*)&lA[0][0];        // [128][4] wave partials
  float* scl = scr + 128 * 4;            // [128] final scales

  float g8[8], c8[8], s8[8];
#pragma unroll
  for (int ni = 0; ni < 8; ++ni) {
    int col = wc * 128 + ni * 16 + lr;
    g8[ni] = wg[col]; c8[ni] = chv[col]; s8[ni] = shv[col];
  }
  int rbase_loc = wr * 64 + ((lane >> 4) << 2);
  int rbase_glb = bm * 128 + rbase_loc;

#pragma unroll
  for (int mi = 0; mi < 4; ++mi) {
    float r1a[4], r2a[4], ssq[4];
#pragma unroll
    for (int j = 0; j < 4; ++j) {
      int m = rbase_glb + mi * 16 + j;
      float un2 = nsq[m] + nsq[m + 16] + nsq[m + 32];
      float un = sqrtf(un2);
      float unc = fmaxf(un, 1e-15f);
      float e2 = fast_exp2(unc * (2.f * LOG2E));
      float th = (e2 - 1.f) * fast_rcp(e2 + 1.f);
      float sxp = th * fast_rcp(unc);        // expmap0 scale (RC=1)
      float cx2 = sxp * sxp * un2;
      float iden = fast_rcp(fmaxf(1.f - cx2, 1e-15f));
      r1a[j] = 2.f * sxp * iden;
      r2a[j] = (1.f + cx2) * iden;
      ssq[j] = 0.f;
    }
#pragma unroll
    for (int ni = 0; ni < 8; ++ni) {
#pragma unroll
      for (int j = 0; j < 4; ++j) {
        float z = r1a[j] * acc[mi][ni][j] * c8[ni] - r2a[j] * s8[ni];
        float w = z + sqrtf(fmaf(z, z, 1.f));
        float l = fast_log2(w);
        float E = fast_exp2((2.f * g8[ni]) * l);
        float y = 0.5f * (E - fast_rcp(E));
        acc[mi][ni][j] = y;
        ssq[j] += y * y;
      }
    }
#pragma unroll
    for (int j = 0; j < 4; ++j) {
#pragma unroll
      for (int d = 1; d < 16; d <<= 1) ssq[j] += __shfl_xor(ssq[j], d);
    }
    if (lr == 0) {
#pragma unroll
      for (int j = 0; j < 4; ++j)
        scr[(rbase_loc + mi * 16 + j) * 4 + wc] = ssq[j];
    }
  }
  __syncthreads();
  if (tid < 128) {
    float ss = scr[tid * 4] + scr[tid * 4 + 1] + scr[tid * 4 + 2] + scr[tid * 4 + 3];
    float denom = 1.f + sqrtf(1.f + ss);
    float idn = 1.f / denom;
    float nrm = fmaxf(sqrtf(ss) * idn, 1e-15f);
    float maxn = 1.0f - 4e-3f;
    float scale = (nrm > maxn) ? (maxn / nrm) : 1.f;
    scl[tid] = scale * idn;
  }
  __syncthreads();

#pragma unroll
  for (int mi = 0; mi < 4; ++mi) {
    float sc4[4];
#pragma unroll
    for (int j = 0; j < 4; ++j) sc4[j] = scl[rbase_loc + mi * 16 + j];
#pragma unroll
    for (int ni = 0; ni < 8; ++ni) {
      int col = wc * 128 + ni * 16 + lr;
#pragma unroll
      for (int j = 0; j < 4; ++j)
        out[(size_t)(rbase_glb + mi * 16 + j) * COUT + col] = acc[mi][ni][j] * sc4[j];
    }
  }
}

extern "C" void kernel_launch(void* const* d_in, const int* in_sizes, int n_in,
                              void* d_out, int out_size, void* d_ws, size_t ws_size,
                              hipStream_t stream) {
  const float* x    = (const float*)d_in[0];
  const float* wg   = (const float*)d_in[1];
  const float* wv   = (const float*)d_in[2];
  const float* bias = (const float*)d_in[3];
  float* out = (float*)d_out;

  char* ws = (char*)d_ws;
  u16*   U    = (u16*)(ws);                    // 2050*16*512 bf16 = 33,587,200 B
  float* NSQ  = (float*)(ws + 33587200);       // 32800 f32      =    131,200 B
  u16*   WT   = (u16*)(ws + 33718400);         // 512*1536 bf16  =  1,572,864 B
  float* INVN = (float*)(ws + 35291264);       // 512 f32
  float* CH   = (float*)(ws + 35293312);       // 512 f32
  float* SH   = (float*)(ws + 35295360);       // 512 f32
  float* PART = (float*)(ws + 35297408);       // 24*512 f32 = 49,152 B

  double lb = (lgamma(768.0) + lgamma(0.5) - lgamma(768.5))
            - (lgamma(256.0) + lgamma(0.5) - lgamma(256.5));
  float beta_ratio = (float)exp(lb);           // beta(768,.5)/beta(256,.5)

  k_colnorm<<<dim3(COUT / 256, KIN / 64), 256, 0, stream>>>(wv, PART);
  k_fin<<<COUT / 256, 256, 0, stream>>>(PART, bias, INVN, CH, SH);
  k_wt<<<dim3(KIN / 64, COUT / 64), 256, 0, stream>>>(wv, INVN, WT);
  k_logmap<<<UROWS, 64, 0, stream>>>(x, U, NSQ, beta_ratio);
  k_gemm<<<NROWS / 128, 512, 0, stream>>>(U, WT, NSQ, wg, CH, SH, out);
}

// Round 12
// 104.429 us; speedup vs baseline: 1.1544x; 1.0055x over previous
//
#include <hip/hip_runtime.h>
#include <cstdint>
#include <cmath>

typedef unsigned short u16;
typedef short bf16x8 __attribute__((ext_vector_type(8)));
typedef float f32x4 __attribute__((ext_vector_type(4)));

#define T_DIM 2048
#define B_DIM 16
#define CIN 512
#define COUT 512
#define KIN 1536
#define NROWS (T_DIM * B_DIM)        /* 32768 */
#define UROWS ((T_DIM + 2) * B_DIM)  /* 32800 */

#define NS 48                        /* K-steps of 32 */

#define LOG2E 1.44269504088896f
#define LN2   0.69314718055995f

__device__ __forceinline__ float fast_exp2(float x) {
#if __has_builtin(__builtin_amdgcn_exp2f)
  return __builtin_amdgcn_exp2f(x);
#else
  return __builtin_exp2f(x);
#endif
}
__device__ __forceinline__ float fast_log2(float x) {
#if __has_builtin(__builtin_amdgcn_logf)
  return __builtin_amdgcn_logf(x);   // v_log_f32 = log2(x)
#else
  return __builtin_log2f(x);
#endif
}
__device__ __forceinline__ float fast_rcp(float x) {
  return __builtin_amdgcn_rcpf(x);
}

__device__ __forceinline__ u16 f2bf(float f) {
  unsigned u = __builtin_bit_cast(unsigned, f);
  u = (u + 0x7FFFu + ((u >> 16) & 1u)) >> 16;   // RNE
  return (u16)u;
}

typedef __attribute__((address_space(3))) unsigned int as3u32;
typedef __attribute__((address_space(1))) unsigned int as1u32;

// async global->LDS, 16B per lane; lds must be the wave-uniform base.
__device__ __forceinline__ void gload16(const u16* g, const u16* lds) {
#if __has_builtin(__builtin_amdgcn_global_load_lds)
  __builtin_amdgcn_global_load_lds((as1u32*)(uintptr_t)g,
                                   (as3u32*)(unsigned)(uintptr_t)lds, 16, 0, 0);
#else
  unsigned lane = __lane_id();
  ((uint4*)lds)[lane] = *(const uint4*)g;
#endif
}

// ---- K0a: partial column sumsq of weight_v [KIN, COUT], coalesced ----
__global__ __launch_bounds__(256) void k_colnorm(const float* __restrict__ wv,
                                                 float* __restrict__ partial) {
  int o = blockIdx.x * 256 + threadIdx.x;
  int r0 = blockIdx.y * 64;
  float s = 0.f;
#pragma unroll 8
  for (int r = 0; r < 64; ++r) {
    float v = wv[(size_t)(r0 + r) * COUT + o];
    s += v * v;
  }
  partial[(size_t)blockIdx.y * COUT + o] = s;
}

// ---- K0c: finalize invn + per-channel cosh/sinh of 2*bias ----
__global__ __launch_bounds__(256) void k_fin(const float* __restrict__ partial,
                                             const float* __restrict__ bias,
                                             float* __restrict__ invn,
                                             float* __restrict__ ch,
                                             float* __restrict__ sh) {
  int o = blockIdx.x * 256 + threadIdx.x;
  float s = 0.f;
#pragma unroll
  for (int j = 0; j < KIN / 64; ++j) s += partial[(size_t)j * COUT + o];
  invn[o] = 1.f / fmaxf(sqrtf(s), 1e-15f);
  float d = 2.f * bias[o];
  float e = fast_exp2(d * LOG2E);
  float ie = fast_rcp(e);
  ch[o] = 0.5f * (e + ie);
  sh[o] = 0.5f * (e - ie);
}

// ---- K1: W^T bf16: wt[o][i] = wv[i][o] * invn[o] ----
__global__ void k_wt(const float* __restrict__ wv, const float* __restrict__ invn,
                     u16* __restrict__ wt) {
  __shared__ float tile[64][65];
  int i0 = blockIdx.x * 64;
  int o0 = blockIdx.y * 64;
  int tx = threadIdx.x & 63, ty = threadIdx.x >> 6;  // 256 thr
  for (int r = ty; r < 64; r += 4)
    tile[r][tx] = wv[(size_t)(i0 + r) * COUT + o0 + tx];
  __syncthreads();
  for (int r = ty; r < 64; r += 4) {
    float inv = invn[o0 + r];
    wt[(size_t)(o0 + r) * KIN + i0 + tx] = f2bf(tile[tx][r] * inv);
  }
}

// ---- K2: u = logmap0(x)*BETA_RATIO -> bf16 [UROWS,512]; nsq fp32 per row ----
__global__ void k_logmap(const float* __restrict__ x, u16* __restrict__ U,
                         float* __restrict__ nsq, float beta_ratio) {
  int row = blockIdx.x;        // 0..32799 = t_pad*16 + b
  int t = row >> 4;
  int lane = threadIdx.x;      // 64
  uint4* urow = (uint4*)(U + (size_t)row * CIN);
  if (t == 0 || t == T_DIM + 1) {
    uint4 z; z.x = z.y = z.z = z.w = 0u;
    urow[lane] = z;
    if (lane == 0) nsq[row] = 0.f;
    return;
  }
  const float4* xr = (const float4*)(x + (size_t)(row - 16) * CIN);
  float4 a = xr[lane * 2];
  float4 b = xr[lane * 2 + 1];
  float s = a.x*a.x + a.y*a.y + a.z*a.z + a.w*a.w
          + b.x*b.x + b.y*b.y + b.z*b.z + b.w*b.w;
#pragma unroll
  for (int d = 1; d < 64; d <<= 1) s += __shfl_xor(s, d);
  float r = sqrtf(s);
  float yn = fmaxf(r, 1e-15f);
  float arg = fminf(yn, 1.0f - 1e-7f);
  float at = 0.5f * LN2 * fast_log2((1.f + arg) * fast_rcp(1.f - arg));
  float f = at / yn * beta_ratio;
  union { u16 h[8]; uint4 v; } pk;
  pk.h[0] = f2bf(a.x * f); pk.h[1] = f2bf(a.y * f);
  pk.h[2] = f2bf(a.z * f); pk.h[3] = f2bf(a.w * f);
  pk.h[4] = f2bf(b.x * f); pk.h[5] = f2bf(b.y * f);
  pk.h[6] = f2bf(b.z * f); pk.h[7] = f2bf(b.w * f);
  urow[lane] = pk.v;
  if (lane == 0) nsq[row] = s * f * f;
}

// ---- K3: fused GEMM + poincare epilogue ----
// Block = 128 rows x 512 cols (full output rows -> in-block projection).
// BK=32, 3-deep LDS ring (A 3x8KB + B 3x32KB = 120 KiB), 2-tile lookahead,
// counted vmcnt(5) per tile (never 0 until tail), ONE barrier per tile.
// INCREMENTAL ADDRESSING: per-thread global pointers advanced by scalar-
// selected constants per step (gB += 32; gA += seg-jump aware delta) --
// no per-step 64-bit address recomputation (round-11 VALUBusy fix).
// Swizzle: phys chunk = c ^ ((row>>1)&3) in 64B rows (2-way = free);
// pre-swizzled global src, linear gload dests.
__global__ __launch_bounds__(512, 2) void k_gemm(const u16* __restrict__ U,
                                                 const u16* __restrict__ WT,
                                                 const float* __restrict__ nsq,
                                                 const float* __restrict__ wg,
                                                 const float* __restrict__ chv,
                                                 const float* __restrict__ shv,
                                                 float* __restrict__ out) {
  __shared__ u16 lA[3][128 * 32];   // 3 x 8 KiB
  __shared__ u16 lB[3][512 * 32];   // 3 x 32 KiB
  int bm = blockIdx.x;              // 256 blocks, 128 rows each
  int tid = threadIdx.x;
  int lane = tid & 63;
  int wid = tid >> 6;
  int wr = wid >> 2, wc = wid & 3;      // wave tile: 64 rows x 128 cols
  int lr = lane & 15;
  int sc = (tid & 3) ^ ((tid >> 3) & 3);            // pre-swizzled src chunk
  int cSwz = ((lane >> 4) ^ ((lr >> 1) & 3)) << 3;  // frag read chunk (u16)
  int ldsOffA = (wr * 64 + lr) * 32 + cSwz;         // loop-invariant
  int ldsOffB = (wc * 128 + lr) * 32 + cSwz;

  f32x4 acc[4][8] = {};

  auto stgA = [&](const u16* g, int p) {
    gload16(g, &lA[p][wid * 512]);
  };
  auto stgB = [&](const u16* g, int p) {
#pragma unroll
    for (int r = 0; r < 4; ++r)
      gload16(g + (size_t)r * (128 * KIN), &lB[p][r * 4096 + wid * 512]);
  };

  // base pointers at t=0 (seg=0, c0=0)
  const u16* gA = U + (size_t)(bm * 128 + (tid >> 2)) * 512 + sc * 8;
  const u16* gB = WT + (size_t)(tid >> 2) * KIN + sc * 8;

  // prologue: stage tiles 0,1 (posA(t)= (t>>4)*8192 + (t&15)*32; t<16: t*32)
  stgA(gA, 0);      stgB(gB, 0);
  stgA(gA + 32, 1); stgB(gB + 32, 1);
  gA += 64; gB += 64;                                // now at t=2
  asm volatile("s_waitcnt vmcnt(5)" ::: "memory");   // tile0 landed
  asm volatile("s_barrier" ::: "memory");

  for (int tt = 0; tt < 16; ++tt) {
#pragma unroll
    for (int u = 0; u < 3; ++u) {
      int t = tt * 3 + u;
      int b = u;                        // t % 3
      int p = (u + 2) % 3;
      if (t + 2 < NS) {
        stgA(gA, p); stgB(gB, p);
        int t2 = t + 2;
        gA += ((t2 & 15) == 15) ? 7712 : 32;   // seg jump folded in
        gB += 32;
      }
      const u16* pA = &lA[b][ldsOffA];
      const u16* pB = &lB[b][ldsOffB];
      bf16x8 af[4], bf[8];
#pragma unroll
      for (int i = 0; i < 4; ++i) af[i] = *(const bf16x8*)(pA + i * 512);
#pragma unroll
      for (int i = 0; i < 8; ++i) bf[i] = *(const bf16x8*)(pB + i * 512);
      __builtin_amdgcn_s_setprio(1);
#pragma unroll
      for (int mi = 0; mi < 4; ++mi)
#pragma unroll
        for (int ni = 0; ni < 8; ++ni)
          acc[mi][ni] = __builtin_amdgcn_mfma_f32_16x16x32_bf16(
              af[mi], bf[ni], acc[mi][ni], 0, 0, 0);
      __builtin_amdgcn_s_setprio(0);
      asm volatile("s_waitcnt lgkmcnt(0)" ::: "memory");  // buf b reads done
      if (t < NS - 2)       asm volatile("s_waitcnt vmcnt(5)" ::: "memory");
      else if (t == NS - 2) asm volatile("s_waitcnt vmcnt(0)" ::: "memory");
      asm volatile("s_barrier" ::: "memory");
    }
  }

  // ---- fused epilogue: all K-loop LDS reads fenced -> reuse lA ----
  float* scr = (float*)&lA[0][0];        // [128][4] wave partials
  float* scl = scr + 128 * 4;            // [128] final scales

  float g8[8], c8[8], s8[8];
#pragma unroll
  for (int ni = 0; ni < 8; ++ni) {
    int col = wc * 128 + ni * 16 + lr;
    g8[ni] = wg[col]; c8[ni] = chv[col]; s8[ni] = shv[col];
  }
  int rbase_loc = wr * 64 + ((lane >> 4) << 2);
  int rbase_glb = bm * 128 + rbase_loc;

#pragma unroll
  for (int mi = 0; mi < 4; ++mi) {
    float r1a[4], r2a[4], ssq[4];
#pragma unroll
    for (int j = 0; j < 4; ++j) {
      int m = rbase_glb + mi * 16 + j;
      float un2 = nsq[m] + nsq[m + 16] + nsq[m + 32];
      float un = sqrtf(un2);
      float unc = fmaxf(un, 1e-15f);
      float e2 = fast_exp2(unc * (2.f * LOG2E));
      float th = (e2 - 1.f) * fast_rcp(e2 + 1.f);
      float sxp = th * fast_rcp(unc);        // expmap0 scale (RC=1)
      float cx2 = sxp * sxp * un2;
      float iden = fast_rcp(fmaxf(1.f - cx2, 1e-15f));
      r1a[j] = 2.f * sxp * iden;
      r2a[j] = (1.f + cx2) * iden;
      ssq[j] = 0.f;
    }
#pragma unroll
    for (int ni = 0; ni < 8; ++ni) {
#pragma unroll
      for (int j = 0; j < 4; ++j) {
        float z = r1a[j] * acc[mi][ni][j] * c8[ni] - r2a[j] * s8[ni];
        float w = z + sqrtf(fmaf(z, z, 1.f));
        float l = fast_log2(w);
        float E = fast_exp2((2.f * g8[ni]) * l);
        float y = 0.5f * (E - fast_rcp(E));
        acc[mi][ni][j] = y;
        ssq[j] += y * y;
      }
    }
#pragma unroll
    for (int j = 0; j < 4; ++j) {
#pragma unroll
      for (int d = 1; d < 16; d <<= 1) ssq[j] += __shfl_xor(ssq[j], d);
    }
    if (lr == 0) {
#pragma unroll
      for (int j = 0; j < 4; ++j)
        scr[(rbase_loc + mi * 16 + j) * 4 + wc] = ssq[j];
    }
  }
  __syncthreads();
  if (tid < 128) {
    float ss = scr[tid * 4] + scr[tid * 4 + 1] + scr[tid * 4 + 2] + scr[tid * 4 + 3];
    float denom = 1.f + sqrtf(1.f + ss);
    float idn = 1.f / denom;
    float nrm = fmaxf(sqrtf(ss) * idn, 1e-15f);
    float maxn = 1.0f - 4e-3f;
    float scale = (nrm > maxn) ? (maxn / nrm) : 1.f;
    scl[tid] = scale * idn;
  }
  __syncthreads();

#pragma unroll
  for (int mi = 0; mi < 4; ++mi) {
    float sc4[4];
#pragma unroll
    for (int j = 0; j < 4; ++j) sc4[j] = scl[rbase_loc + mi * 16 + j];
#pragma unroll
    for (int ni = 0; ni < 8; ++ni) {
      int col = wc * 128 + ni * 16 + lr;
#pragma unroll
      for (int j = 0; j < 4; ++j)
        out[(size_t)(rbase_glb + mi * 16 + j) * COUT + col] = acc[mi][ni][j] * sc4[j];
    }
  }
}

extern "C" void kernel_launch(void* const* d_in, const int* in_sizes, int n_in,
                              void* d_out, int out_size, void* d_ws, size_t ws_size,
                              hipStream_t stream) {
  const float* x    = (const float*)d_in[0];
  const float* wg   = (const float*)d_in[1];
  const float* wv   = (const float*)d_in[2];
  const float* bias = (const float*)d_in[3];
  float* out = (float*)d_out;

  char* ws = (char*)d_ws;
  u16*   U    = (u16*)(ws);                    // 2050*16*512 bf16 = 33,587,200 B
  float* NSQ  = (float*)(ws + 33587200);       // 32800 f32      =    131,200 B
  u16*   WT   = (u16*)(ws + 33718400);         // 512*1536 bf16  =  1,572,864 B
  float* INVN = (float*)(ws + 35291264);       // 512 f32
  float* CH   = (float*)(ws + 35293312);       // 512 f32
  float* SH   = (float*)(ws + 35295360);       // 512 f32
  float* PART = (float*)(ws + 35297408);       // 24*512 f32 = 49,152 B

  double lb = (lgamma(768.0) + lgamma(0.5) - lgamma(768.5))
            - (lgamma(256.0) + lgamma(0.5) - lgamma(256.5));
  float beta_ratio = (float)exp(lb);           // beta(768,.5)/beta(256,.5)

  k_colnorm<<<dim3(COUT / 256, KIN / 64), 256, 0, stream>>>(wv, PART);
  k_fin<<<COUT / 256, 256, 0, stream>>>(PART, bias, INVN, CH, SH);
  k_wt<<<dim3(KIN / 64, COUT / 64), 256, 0, stream>>>(wv, INVN, WT);
  k_logmap<<<UROWS, 64, 0, stream>>>(x, U, NSQ, beta_ratio);
  k_gemm<<<NROWS / 128, 512, 0, stream>>>(U, WT, NSQ, wg, CH, SH, out);
}